// Round 10
// baseline (113.750 us; speedup 1.0000x reference)
//
#include <hip/hip_runtime.h>
#include <hip/hip_bf16.h>

// ---------------------------------------------------------------------------
// Adapter: LayerNorm(2048) -> down(64) -> ReLU -> up(2048), 16384 tokens fp32.
// LN folded into down-proj (x read once):
//   down[n] = rstd*( dot(wg[n],x) - mu*s[n] ) + c[n],  wg = bf16(w_down*gamma)
// R10: NO LDS in the down loop. Each lane loads its MFMA A-fragment DIRECTLY
// from global x (16 rows x 128B fully-consumed lines -> zero over-fetch);
// weights fragment-major (coalesced). LN stats from the same registers +
// 4-lane shfl. 64-step loop: 2 x-loads + 1 w-load + cvt + MFMA, no barriers.
// Only 2 barriers in the whole kernel (down-tile exchange). Up = R5 verbatim.
// ---------------------------------------------------------------------------

typedef __attribute__((ext_vector_type(8))) short short8;   // 8 x bf16
typedef __attribute__((ext_vector_type(4))) float f32x4;

#define D_MODEL 2048
#define BNECK   64
#define EPS     1e-5f

__device__ inline short f2bf(float f) {                     // prep only
    unsigned int u = __builtin_bit_cast(unsigned int, f);
    unsigned int r = (u + 0x7fffu + ((u >> 16) & 1u)) >> 16; // RNE
    return (short)r;
}
__device__ inline float bf2f(short s) {
    unsigned int u = ((unsigned int)(unsigned short)s) << 16;
    return __builtin_bit_cast(float, u);
}
__device__ inline short hbf(float f) {                      // HW RNE cvt
    __hip_bfloat16 h = __float2bfloat16(f);
    return __builtin_bit_cast(short, h);
}

// ---------------------------------------------------------------------------
// Prep. wg_perm slot = (n>>4)*64 + (k>>5): per-wave contiguous 64KB stream.
// Within slot: lane l = ((k>>3)&3)*16 + (n&15), elem e = k&7.
// wup_perm: slot (b16*2+h): lane l -> (d=b16*16+(l&15), kn=h*32+(l>>4)*8+e).
// s[n] = sum_k bf16(wg), c[n] = w_down[n,:].beta + b_down[n].
// ---------------------------------------------------------------------------
__global__ __launch_bounds__(256) void prep_kernel(
    const float* __restrict__ w_down, const float* __restrict__ gamma,
    const float* __restrict__ beta,   const float* __restrict__ b_down,
    const float* __restrict__ w_up,
    short* __restrict__ wg_perm, short* __restrict__ wup_perm,
    float* __restrict__ s_out, float* __restrict__ c_out)
{
    __shared__ float rs[4], rc[4];
    int b = blockIdx.x;
    if (b < BNECK) {
        int n = b, nf = n >> 4;
        float ps = 0.f, pc = 0.f;
        for (int d = threadIdx.x; d < D_MODEL; d += 256) {
            float wv = w_down[n * D_MODEL + d];
            short h  = f2bf(wv * gamma[d]);
            int t = d >> 5, kg = (d >> 3) & 3, e = d & 7;
            int l = kg * 16 + (n & 15);
            wg_perm[(size_t)((nf * 64 + t) * 64 + l) * 8 + e] = h;
            ps += bf2f(h);
            pc  = fmaf(wv, beta[d], pc);
        }
        for (int o = 32; o > 0; o >>= 1) {
            ps += __shfl_down(ps, o, 64);
            pc += __shfl_down(pc, o, 64);
        }
        int wid = threadIdx.x >> 6, lane = threadIdx.x & 63;
        if (lane == 0) { rs[wid] = ps; rc[wid] = pc; }
        __syncthreads();
        if (threadIdx.x == 0) {
            s_out[n] = rs[0] + rs[1] + rs[2] + rs[3];
            c_out[n] = rc[0] + rc[1] + rc[2] + rc[3] + b_down[n];
        }
    } else {
        for (int j = (b - BNECK) * 256 + threadIdx.x; j < D_MODEL * BNECK;
             j += 64 * 256) {
            int d = j >> 6, kn = j & 63;
            int b16 = d >> 4, h2 = kn >> 5, e = kn & 7;
            int l = ((kn >> 3) & 3) * 16 + (d & 15);
            wup_perm[(size_t)((b16 * 2 + h2) * 64 + l) * 8 + e] = f2bf(w_up[j]);
        }
    }
}

// ---------------------------------------------------------------------------
// Main kernel. 1024 blocks x 256 threads; block = 16 tokens; waves n-split.
// ---------------------------------------------------------------------------
__global__ __launch_bounds__(256, 4) void adapter_kernel(
    const float* __restrict__ x,    const float* __restrict__ b_up,
    const short* __restrict__ wg_perm, const short* __restrict__ wup_perm,
    const float* __restrict__ s_v,  const float* __restrict__ c_v,
    float* __restrict__ out)
{
    __shared__ __align__(16) char tilebuf[2048];   // 16x64 bf16, swizzled
    __shared__ float stats2[16][2];                // per-token (mu, rstd)

    const int wid  = threadIdx.x >> 6;
    const int lane = threadIdx.x & 63;
    const int r    = lane & 15;          // token row within tile
    const int g    = lane >> 4;          // k-group
    const int row0 = blockIdx.x * 16;
    const int swz  = (r & 7) << 4;

    // ---- down-GEMM: direct-from-global A-fragments, no LDS, no barriers ---
    const float* xr    = x + (size_t)(row0 + r) * D_MODEL + g * 8;
    const short* wbase = wg_perm + (size_t)(wid * 64) * 512 + lane * 8;

    f32x4 accA = (f32x4){0.f, 0.f, 0.f, 0.f};
    f32x4 accB = (f32x4){0.f, 0.f, 0.f, 0.f};
    float ssum = 0.f, ssq = 0.f;

#pragma unroll 8
    for (int s = 0; s < 64; ++s) {
        f32x4 xa = *(const f32x4*)(xr + s * 32);
        f32x4 xb = *(const f32x4*)(xr + s * 32 + 4);
        short8 w = *(const short8*)(wbase + (size_t)s * 512);

        ssum += ((xa.x + xa.y) + (xa.z + xa.w)) +
                ((xb.x + xb.y) + (xb.z + xb.w));
        ssq = fmaf(xa.x, xa.x, ssq); ssq = fmaf(xa.y, xa.y, ssq);
        ssq = fmaf(xa.z, xa.z, ssq); ssq = fmaf(xa.w, xa.w, ssq);
        ssq = fmaf(xb.x, xb.x, ssq); ssq = fmaf(xb.y, xb.y, ssq);
        ssq = fmaf(xb.z, xb.z, ssq); ssq = fmaf(xb.w, xb.w, ssq);

        short8 af;
        af[0] = hbf(xa.x); af[1] = hbf(xa.y);
        af[2] = hbf(xa.z); af[3] = hbf(xa.w);
        af[4] = hbf(xb.x); af[5] = hbf(xb.y);
        af[6] = hbf(xb.z); af[7] = hbf(xb.w);

        if (s & 1)
            accB = __builtin_amdgcn_mfma_f32_16x16x32_bf16(af, w, accB, 0, 0, 0);
        else
            accA = __builtin_amdgcn_mfma_f32_16x16x32_bf16(af, w, accA, 0, 0, 0);
    }
    f32x4 acc = accA + accB;

    // ---- LN stats: lane covers (row r, k-slice g); reduce over g ----------
    ssum += __shfl_xor(ssum, 16, 64); ssum += __shfl_xor(ssum, 32, 64);
    ssq  += __shfl_xor(ssq , 16, 64); ssq  += __shfl_xor(ssq , 32, 64);
    float mu   = ssum * (1.f / D_MODEL);
    float rstd = rsqrtf(ssq * (1.f / D_MODEL) - mu * mu + EPS);
    if (lane < 16) { stats2[r][0] = mu; stats2[r][1] = rstd; }
    __syncthreads();                      // (1) stats visible

    // ---- fix-up + ReLU: wave owns n = wid*16 + r, tokens m = g*4+reg ------
    {
        int   n  = wid * 16 + r;
        float sn = s_v[n], cn = c_v[n];
#pragma unroll
        for (int reg = 0; reg < 4; ++reg) {
            int   m = g * 4 + reg;
            float v = fmaf(stats2[m][1], acc[reg] - stats2[m][0] * sn, cn);
            v = fmaxf(v, 0.f);
            *(short*)(tilebuf + ((m * 128 + n * 2) ^ ((m & 7) << 4))) = hbf(v);
        }
    }
    __syncthreads();                      // (2) down tile ready

    // ---- up-GEMM (A = w_up fragment-major, B = down^T), R5 verbatim -------
    short8 bd0 = *(const short8*)(tilebuf + ((r * 128 +  0 + g * 16) ^ swz));
    short8 bd1 = *(const short8*)(tilebuf + ((r * 128 + 64 + g * 16) ^ swz));

    const short* wupl = wup_perm + lane * 8;
    float* outr = out + (size_t)(row0 + r) * D_MODEL;

    short8 ua[2], ub[2];
    {
        int b16 = wid * 32;
        ua[0] = *(const short8*)(wupl + (size_t)(b16 * 2 + 0) * 512);
        ub[0] = *(const short8*)(wupl + (size_t)(b16 * 2 + 1) * 512);
    }
#pragma unroll
    for (int i = 0; i < 32; ++i) {
        int cur = i & 1;
        if (i < 31) {
            int b16 = wid * 32 + i + 1;
            ua[cur ^ 1] = *(const short8*)(wupl + (size_t)(b16 * 2 + 0) * 512);
            ub[cur ^ 1] = *(const short8*)(wupl + (size_t)(b16 * 2 + 1) * 512);
        }
        f32x4 o = (f32x4){0.f, 0.f, 0.f, 0.f};
        o = __builtin_amdgcn_mfma_f32_16x16x32_bf16(ua[cur], bd0, o, 0, 0, 0);
        o = __builtin_amdgcn_mfma_f32_16x16x32_bf16(ub[cur], bd1, o, 0, 0, 0);
        int dbase = (wid * 32 + i) * 16;
        f32x4 bu = *(const f32x4*)(b_up + dbase + g * 4);
        *(f32x4*)(outr + dbase + g * 4) = o + bu;
    }
}

extern "C" void kernel_launch(void* const* d_in, const int* in_sizes, int n_in,
                              void* d_out, int out_size, void* d_ws, size_t ws_size,
                              hipStream_t stream) {
    const float* x      = (const float*)d_in[0];
    const float* gamma  = (const float*)d_in[1];
    const float* beta   = (const float*)d_in[2];
    const float* w_down = (const float*)d_in[3];
    const float* b_down = (const float*)d_in[4];
    const float* w_up   = (const float*)d_in[5];
    const float* b_up   = (const float*)d_in[6];
    float* out = (float*)d_out;

    char* ws = (char*)d_ws;
    short* wg_perm  = (short*)ws;                 // 256 KB
    short* wup_perm = (short*)(ws + 262144);      // 256 KB
    float* s_v  = (float*)(ws + 524288);          // 256 B
    float* c_v  = (float*)(ws + 524544);          // 256 B

    prep_kernel<<<128, 256, 0, stream>>>(w_down, gamma, beta, b_down, w_up,
                                         wg_perm, wup_perm, s_v, c_v);
    adapter_kernel<<<1024, 256, 0, stream>>>(x, b_up, wg_perm, wup_perm,
                                             s_v, c_v, out);
}

// Round 11
// 80.733 us; speedup vs baseline: 1.4090x; 1.4090x over previous
//
#include <hip/hip_runtime.h>
#include <hip/hip_bf16.h>

// ---------------------------------------------------------------------------
// Adapter: LayerNorm(2048) -> down(64) -> ReLU -> up(2048), 16384 tokens fp32.
// LN folded into down-proj (x read once):
//   down[n] = rstd*( dot(wg[n],x) - mu*s[n] ) + c[n],  wg = bf16(w_down*gamma)
// R11 = R5 (best, 68us) with the sync/traffic knobs turned, protocol intact:
//  - chunk K 64->128: barriers/block 34 -> 18
//  - bf16 conversion AT STAGING (stats on f32 regs first): LDS bytes halved,
//    cvt once per element (was 4x), inner loop = ds_read_b128 + MFMA only
//  - x reg-prefetch 3 chunks deep; weights 1 chunk ahead (4x1KB coalesced)
// ---------------------------------------------------------------------------

typedef __attribute__((ext_vector_type(8))) short short8;   // 8 x bf16
typedef __attribute__((ext_vector_type(4))) float f32x4;

#define D_MODEL 2048
#define BNECK   64
#define EPS     1e-5f
#define NCH     16          // chunks of K=128 f32 (512B/row f32, 256B bf16)

__device__ inline short f2bf(float f) {                     // prep only
    unsigned int u = __builtin_bit_cast(unsigned int, f);
    unsigned int r = (u + 0x7fffu + ((u >> 16) & 1u)) >> 16; // RNE
    return (short)r;
}
__device__ inline float bf2f(short s) {
    unsigned int u = ((unsigned int)(unsigned short)s) << 16;
    return __builtin_bit_cast(float, u);
}
__device__ inline short hbf(float f) {                      // HW RNE cvt
    __hip_bfloat16 h = __float2bfloat16(f);
    return __builtin_bit_cast(short, h);
}

// ---------------------------------------------------------------------------
// Prep. wg_perm slot = (n>>4)*64 + (k>>5): per-wave contiguous 64KB stream.
// Within slot: lane l = ((k>>3)&3)*16 + (n&15), elem e = k&7.
// wup_perm: slot (b16*2+h): lane l -> (d=b16*16+(l&15), kn=h*32+(l>>4)*8+e).
// s[n] = sum_k bf16(wg), c[n] = w_down[n,:].beta + b_down[n].
// ---------------------------------------------------------------------------
__global__ __launch_bounds__(256) void prep_kernel(
    const float* __restrict__ w_down, const float* __restrict__ gamma,
    const float* __restrict__ beta,   const float* __restrict__ b_down,
    const float* __restrict__ w_up,
    short* __restrict__ wg_perm, short* __restrict__ wup_perm,
    float* __restrict__ s_out, float* __restrict__ c_out)
{
    __shared__ float rs[4], rc[4];
    int b = blockIdx.x;
    if (b < BNECK) {
        int n = b, nf = n >> 4;
        float ps = 0.f, pc = 0.f;
        for (int d = threadIdx.x; d < D_MODEL; d += 256) {
            float wv = w_down[n * D_MODEL + d];
            short h  = f2bf(wv * gamma[d]);
            int t = d >> 5, kg = (d >> 3) & 3, e = d & 7;
            int l = kg * 16 + (n & 15);
            wg_perm[(size_t)((nf * 64 + t) * 64 + l) * 8 + e] = h;
            ps += bf2f(h);
            pc  = fmaf(wv, beta[d], pc);
        }
        for (int o = 32; o > 0; o >>= 1) {
            ps += __shfl_down(ps, o, 64);
            pc += __shfl_down(pc, o, 64);
        }
        int wid = threadIdx.x >> 6, lane = threadIdx.x & 63;
        if (lane == 0) { rs[wid] = ps; rc[wid] = pc; }
        __syncthreads();
        if (threadIdx.x == 0) {
            s_out[n] = rs[0] + rs[1] + rs[2] + rs[3];
            c_out[n] = rc[0] + rc[1] + rc[2] + rc[3] + b_down[n];
        }
    } else {
        for (int j = (b - BNECK) * 256 + threadIdx.x; j < D_MODEL * BNECK;
             j += 64 * 256) {
            int d = j >> 6, kn = j & 63;
            int b16 = d >> 4, h2 = kn >> 5, e = kn & 7;
            int l = ((kn >> 3) & 3) * 16 + (d & 15);
            wup_perm[(size_t)((b16 * 2 + h2) * 64 + l) * 8 + e] = f2bf(w_up[j]);
        }
    }
}

// ---------------------------------------------------------------------------
// Main kernel. 1024 blocks x 256 threads; block owns 16 tokens; waves n-split.
// ---------------------------------------------------------------------------
__global__ __launch_bounds__(256, 4) void adapter_kernel(
    const float* __restrict__ x,    const float* __restrict__ b_up,
    const short* __restrict__ wg_perm, const short* __restrict__ wup_perm,
    const float* __restrict__ s_v,  const float* __restrict__ c_v,
    float* __restrict__ out)
{
    __shared__ __align__(16) char xbuf[2][4096];   // dbuf: 16 rows x 256B bf16
    __shared__ __align__(16) char tilebuf[2048];   // 16x64 bf16, swizzled
    __shared__ float stats2[16][2];                // per-token (mu, rstd)

    const int tid  = threadIdx.x;
    const int wid  = tid >> 6;
    const int lane = tid & 63;
    const int r    = lane & 15;          // frag row/col index
    const int g    = lane >> 4;          // k-group
    const int row0 = blockIdx.x * 16;
    const int swz  = (r & 7) << 4;

    // ---- staging: row sr = wid*4+g (16 consecutive lanes), 32B slice j=r --
    const int sr = wid * 4 + g;          // == tid>>4
    const int j  = r;                    // == tid&15
    const float* xsrc = x + (size_t)(row0 + sr) * D_MODEL + j * 8;
    char* const swdst = &xbuf[0][0] + sr * 256 + ((j * 16) ^ ((sr & 7) << 4));

    const short* wbase = wg_perm + (size_t)(wid * 64) * 512 + lane * 8;

    f32x4  xr[4][2];         // x chunks in regs, 3 in flight (32B each)
    short8 wb[2][4];         // weight frags, 1 chunk ahead (K=128 -> 4 frags)
    f32x4  accA = (f32x4){0.f, 0.f, 0.f, 0.f};
    f32x4  accB = (f32x4){0.f, 0.f, 0.f, 0.f};
    float  ssum = 0.f, ssq = 0.f;

    auto LDX = [&](int c, f32x4* o) {
        o[0] = *(const f32x4*)(xsrc + (size_t)c * 128);
        o[1] = *(const f32x4*)(xsrc + (size_t)c * 128 + 4);
    };
    auto LDW = [&](int c, short8* w) {
#pragma unroll
        for (int k = 0; k < 4; ++k)
            w[k] = *(const short8*)(wbase + (size_t)(c * 4 + k) * 512);
    };
    // stats on f32 regs, convert ONCE to bf16, single ds_write_b128
    auto STATS_CVT_WRITE = [&](int c, const f32x4* v) {
#pragma unroll
        for (int h = 0; h < 2; ++h) {
            ssum += (v[h].x + v[h].y) + (v[h].z + v[h].w);
            ssq = fmaf(v[h].x, v[h].x, ssq); ssq = fmaf(v[h].y, v[h].y, ssq);
            ssq = fmaf(v[h].z, v[h].z, ssq); ssq = fmaf(v[h].w, v[h].w, ssq);
        }
        short8 u;
        u[0] = hbf(v[0].x); u[1] = hbf(v[0].y); u[2] = hbf(v[0].z); u[3] = hbf(v[0].w);
        u[4] = hbf(v[1].x); u[5] = hbf(v[1].y); u[6] = hbf(v[1].z); u[7] = hbf(v[1].w);
        *(short8*)(swdst + (size_t)(c & 1) * 4096) = u;
    };

    // prologue: 3 chunks of x in flight, weights 1 chunk ahead
    LDX(0, xr[0]); LDX(1, xr[1]); LDX(2, xr[2]);
    LDW(0, wb[0]);
    STATS_CVT_WRITE(0, xr[0]);

#pragma unroll
    for (int c = 0; c < NCH; ++c) {
        if (c + 3 < NCH) LDX(c + 3, xr[(c + 3) & 3]);
        if (c + 1 < NCH) LDW(c + 1, wb[(c + 1) & 1]);
        // drain my ds ops; barrier certifies buf[(c+1)&1] free + buf[c] ready
        asm volatile("s_waitcnt lgkmcnt(0)\n\ts_barrier" ::: "memory");
        if (c + 1 < NCH) STATS_CVT_WRITE(c + 1, xr[(c + 1) & 3]);

        const char* bp = &xbuf[c & 1][0];
        const short8* w = wb[c & 1];
#pragma unroll
        for (int kk = 0; kk < 4; ++kk) {
            short8 af = *(const short8*)(bp + r * 256 + ((kk * 64 + g * 16) ^ swz));
            if (kk & 1)
                accB = __builtin_amdgcn_mfma_f32_16x16x32_bf16(af, w[kk], accB, 0, 0, 0);
            else
                accA = __builtin_amdgcn_mfma_f32_16x16x32_bf16(af, w[kk], accA, 0, 0, 0);
        }
    }
    f32x4 acc = accA + accB;

    // ---- LN stats: 16 consecutive lanes share row sr -----------------------
#pragma unroll
    for (int m = 1; m < 16; m <<= 1) {
        ssum += __shfl_xor(ssum, m, 64);
        ssq  += __shfl_xor(ssq , m, 64);
    }
    float mu   = ssum * (1.f / D_MODEL);
    float rstd = rsqrtf(ssq * (1.f / D_MODEL) - mu * mu + EPS);
    if (j == 0) { stats2[sr][0] = mu; stats2[sr][1] = rstd; }
    __syncthreads();                      // stats visible

    // ---- fix-up + ReLU: wave owns n = wid*16 + r, tokens m = g*4+reg ------
    {
        int   n  = wid * 16 + r;
        float sn = s_v[n], cn = c_v[n];
#pragma unroll
        for (int reg = 0; reg < 4; ++reg) {
            int   m = g * 4 + reg;
            float v = fmaf(stats2[m][1], acc[reg] - stats2[m][0] * sn, cn);
            v = fmaxf(v, 0.f);
            *(short*)(tilebuf + ((m * 128 + n * 2) ^ ((m & 7) << 4))) = hbf(v);
        }
    }
    __syncthreads();                      // down tile ready

    // ---- up-GEMM (A = w_up fragment-major, B = down^T), R5 verbatim -------
    short8 bd0 = *(const short8*)(tilebuf + ((r * 128 +  0 + g * 16) ^ swz));
    short8 bd1 = *(const short8*)(tilebuf + ((r * 128 + 64 + g * 16) ^ swz));

    const short* wupl = wup_perm + lane * 8;
    float* outr = out + (size_t)(row0 + r) * D_MODEL;

    short8 ua[2], ub[2];
    {
        int b16 = wid * 32;
        ua[0] = *(const short8*)(wupl + (size_t)(b16 * 2 + 0) * 512);
        ub[0] = *(const short8*)(wupl + (size_t)(b16 * 2 + 1) * 512);
    }
#pragma unroll
    for (int i = 0; i < 32; ++i) {
        int cur = i & 1;
        if (i < 31) {
            int b16 = wid * 32 + i + 1;
            ua[cur ^ 1] = *(const short8*)(wupl + (size_t)(b16 * 2 + 0) * 512);
            ub[cur ^ 1] = *(const short8*)(wupl + (size_t)(b16 * 2 + 1) * 512);
        }
        f32x4 o = (f32x4){0.f, 0.f, 0.f, 0.f};
        o = __builtin_amdgcn_mfma_f32_16x16x32_bf16(ua[cur], bd0, o, 0, 0, 0);
        o = __builtin_amdgcn_mfma_f32_16x16x32_bf16(ub[cur], bd1, o, 0, 0, 0);
        int dbase = (wid * 32 + i) * 16;
        f32x4 bu = *(const f32x4*)(b_up + dbase + g * 4);
        *(f32x4*)(outr + dbase + g * 4) = o + bu;
    }
}

extern "C" void kernel_launch(void* const* d_in, const int* in_sizes, int n_in,
                              void* d_out, int out_size, void* d_ws, size_t ws_size,
                              hipStream_t stream) {
    const float* x      = (const float*)d_in[0];
    const float* gamma  = (const float*)d_in[1];
    const float* beta   = (const float*)d_in[2];
    const float* w_down = (const float*)d_in[3];
    const float* b_down = (const float*)d_in[4];
    const float* w_up   = (const float*)d_in[5];
    const float* b_up   = (const float*)d_in[6];
    float* out = (float*)d_out;

    char* ws = (char*)d_ws;
    short* wg_perm  = (short*)ws;                 // 256 KB
    short* wup_perm = (short*)(ws + 262144);      // 256 KB
    float* s_v  = (float*)(ws + 524288);          // 256 B
    float* c_v  = (float*)(ws + 524544);          // 256 B

    prep_kernel<<<128, 256, 0, stream>>>(w_down, gamma, beta, b_down, w_up,
                                         wg_perm, wup_perm, s_v, c_v);
    adapter_kernel<<<1024, 256, 0, stream>>>(x, b_up, wg_perm, wup_perm,
                                             s_v, c_v, out);
}

// Round 13
// 70.097 us; speedup vs baseline: 1.6227x; 1.1517x over previous
//
#include <hip/hip_runtime.h>
#include <hip/hip_bf16.h>

// ---------------------------------------------------------------------------
// Adapter: LayerNorm(2048) -> down(64) -> ReLU -> up(2048), 16384 tokens fp32.
// LN folded into down-proj (x read once):
//   down[n] = rstd*( dot(wg[n],x) - mu*s[n] ) + c[n],  wg = bf16(w_down*gamma)
// R13 = R12 with the OOB fix: coalesced-store base row is row0 + g (token
//   t = q*4+g lives at row0 + g + q*4). R12's `4*g` wrote past the buffer.
// Change vs R5 (68us baseline) is ONLY the up-phase stores:
//   16-segment divergent f32x4 stores  ->  per-wave padded LDS bounce +
//   4-segment x 256B contiguous stores (4x fewer store requests).
// ---------------------------------------------------------------------------

typedef __attribute__((ext_vector_type(8))) short short8;   // 8 x bf16
typedef __attribute__((ext_vector_type(4))) float f32x4;

#define D_MODEL 2048
#define BNECK   64
#define EPS     1e-5f
#define NCHUNK  32          // chunks of K=64 (256B per row)

__device__ inline short f2bf(float f) {                     // prep only
    unsigned int u = __builtin_bit_cast(unsigned int, f);
    unsigned int r = (u + 0x7fffu + ((u >> 16) & 1u)) >> 16; // RNE
    return (short)r;
}
__device__ inline float bf2f(short s) {
    unsigned int u = ((unsigned int)(unsigned short)s) << 16;
    return __builtin_bit_cast(float, u);
}
__device__ inline short hbf(float f) {                      // HW RNE cvt
    __hip_bfloat16 h = __float2bfloat16(f);
    return __builtin_bit_cast(short, h);
}

// ---------------------------------------------------------------------------
// Prep. wg_perm slot = (n>>4)*64 + (k>>5): per-wave contiguous 64KB stream.
// Within slot: lane l = ((k>>3)&3)*16 + (n&15), elem e = k&7.
// wup_perm: slot (b16*2+h): lane l -> (d=b16*16+(l&15), kn=h*32+(l>>4)*8+e).
// s[n] = sum_k bf16(wg), c[n] = w_down[n,:].beta + b_down[n].
// ---------------------------------------------------------------------------
__global__ __launch_bounds__(256) void prep_kernel(
    const float* __restrict__ w_down, const float* __restrict__ gamma,
    const float* __restrict__ beta,   const float* __restrict__ b_down,
    const float* __restrict__ w_up,
    short* __restrict__ wg_perm, short* __restrict__ wup_perm,
    float* __restrict__ s_out, float* __restrict__ c_out)
{
    __shared__ float rs[4], rc[4];
    int b = blockIdx.x;
    if (b < BNECK) {
        int n = b, nf = n >> 4;
        float ps = 0.f, pc = 0.f;
        for (int d = threadIdx.x; d < D_MODEL; d += 256) {
            float wv = w_down[n * D_MODEL + d];
            short h  = f2bf(wv * gamma[d]);
            int t = d >> 5, kg = (d >> 3) & 3, e = d & 7;
            int l = kg * 16 + (n & 15);
            wg_perm[(size_t)((nf * 64 + t) * 64 + l) * 8 + e] = h;
            ps += bf2f(h);
            pc  = fmaf(wv, beta[d], pc);
        }
        for (int o = 32; o > 0; o >>= 1) {
            ps += __shfl_down(ps, o, 64);
            pc += __shfl_down(pc, o, 64);
        }
        int wid = threadIdx.x >> 6, lane = threadIdx.x & 63;
        if (lane == 0) { rs[wid] = ps; rc[wid] = pc; }
        __syncthreads();
        if (threadIdx.x == 0) {
            s_out[n] = rs[0] + rs[1] + rs[2] + rs[3];
            c_out[n] = rc[0] + rc[1] + rc[2] + rc[3] + b_down[n];
        }
    } else {
        for (int j = (b - BNECK) * 256 + threadIdx.x; j < D_MODEL * BNECK;
             j += 64 * 256) {
            int d = j >> 6, kn = j & 63;
            int b16 = d >> 4, h2 = kn >> 5, e = kn & 7;
            int l = ((kn >> 3) & 3) * 16 + (d & 15);
            wup_perm[(size_t)((b16 * 2 + h2) * 64 + l) * 8 + e] = f2bf(w_up[j]);
        }
    }
}

// ---------------------------------------------------------------------------
// Main kernel. 1024 blocks x 256 threads; block owns 16 tokens; waves n-split.
// ---------------------------------------------------------------------------
__global__ __launch_bounds__(256, 4) void adapter_kernel(
    const float* __restrict__ x,    const float* __restrict__ b_up,
    const short* __restrict__ wg_perm, const short* __restrict__ wup_perm,
    const float* __restrict__ s_v,  const float* __restrict__ c_v,
    float* __restrict__ out)
{
    __shared__ __align__(16) char xbuf[2][4096];   // shared dbuf: 16 rows x 256B
    __shared__ __align__(16) char tilebuf[2048];   // 16x64 bf16, swizzled
    __shared__ float stats2[16][2];                // per-token (mu, rstd)
    __shared__ __align__(16) float obuf[4][16][65]; // per-wave out section

    const int wid  = threadIdx.x >> 6;
    const int lane = threadIdx.x & 63;
    const int r    = lane & 15;          // frag row/col index
    const int g    = lane >> 4;          // k-group
    const int row0 = blockIdx.x * 16;
    const int swz  = (r & 7) << 4;

    // ---- cooperative staging: wave wid owns rows [wid*4, wid*4+4) ---------
    const int srow = wid * 4 + g;                  // this lane's staged row
    const int scol = r * 16;                       // byte col within 256B chunk
    const char* xsrc = (const char*)x
        + ((size_t)(row0 + srow) * D_MODEL) * 4 + scol;
    char* const swdst = &xbuf[0][0] + srow * 256 + (scol ^ ((srow & 7) << 4));

    const short* wbase = wg_perm + (size_t)(wid * 64) * 512 + lane * 8;

    f32x4  xr[4];            // register-staged x chunks (3 in flight)
    short8 wb[2][2];         // weight frags, 1 chunk ahead
    f32x4  acc = (f32x4){0.f, 0.f, 0.f, 0.f};
    float  ssum = 0.f, ssq = 0.f;

    auto LDX = [&](int c) { return *(const f32x4*)(xsrc + c * 256); };
    auto LDW = [&](int c, short8* w) {
        w[0] = *(const short8*)(wbase + (size_t)(c * 2 + 0) * 512);
        w[1] = *(const short8*)(wbase + (size_t)(c * 2 + 1) * 512);
    };
    auto STATS_WRITE = [&](int c, const f32x4& v) {   // stats + publish to LDS
        ssum += (v.x + v.y) + (v.z + v.w);
        ssq = fmaf(v.x, v.x, ssq); ssq = fmaf(v.y, v.y, ssq);
        ssq = fmaf(v.z, v.z, ssq); ssq = fmaf(v.w, v.w, ssq);
        *(f32x4*)(swdst + (size_t)(c & 1) * 4096) = v;    // ds_write_b128
    };

    // prologue: 3 chunks of x in flight, weights 1 chunk ahead
    xr[0] = LDX(0); xr[1] = LDX(1); xr[2] = LDX(2);
    LDW(0, wb[0]);
    STATS_WRITE(0, xr[0]);

#pragma unroll
    for (int c = 0; c < NCHUNK; ++c) {
        if (c + 3 < NCHUNK) xr[(c + 3) & 3] = LDX(c + 3);
        if (c + 1 < NCHUNK) LDW(c + 1, wb[(c + 1) & 1]);
        // publish writes of chunk c, certify reads of buf[(c+1)&1] finished
        asm volatile("s_waitcnt lgkmcnt(0)\n\ts_barrier" ::: "memory");
        if (c + 1 < NCHUNK) STATS_WRITE(c + 1, xr[(c + 1) & 3]);

        const char* bp = &xbuf[c & 1][0];
        const short8* w = wb[c & 1];
#pragma unroll
        for (int kb = 0; kb < 2; ++kb) {
            int cb = kb * 128 + g * 32;
            f32x4 xa = *(const f32x4*)(bp + r * 256 + ( cb        ^ swz));
            f32x4 xb = *(const f32x4*)(bp + r * 256 + ((cb + 16)  ^ swz));
            short8 af;
            af[0] = hbf(xa.x); af[1] = hbf(xa.y);
            af[2] = hbf(xa.z); af[3] = hbf(xa.w);
            af[4] = hbf(xb.x); af[5] = hbf(xb.y);
            af[6] = hbf(xb.z); af[7] = hbf(xb.w);
            acc = __builtin_amdgcn_mfma_f32_16x16x32_bf16(af, w[kb], acc, 0, 0, 0);
        }
    }

    // ---- LN stats for this wave's 4 staged rows (reduce over 16 lanes) ----
#pragma unroll
    for (int m = 1; m < 16; m <<= 1) {
        ssum += __shfl_xor(ssum, m, 64);
        ssq  += __shfl_xor(ssq , m, 64);
    }
    float mu   = ssum * (1.f / D_MODEL);
    float rstd = rsqrtf(ssq * (1.f / D_MODEL) - mu * mu + EPS);
    if (r == 0) { stats2[srow][0] = mu; stats2[srow][1] = rstd; }
    __syncthreads();

    // ---- fix-up + ReLU: wave owns n = wid*16 + r, tokens m = g*4+reg ------
    {
        int   n  = wid * 16 + r;
        float sn = s_v[n], cn = c_v[n];
#pragma unroll
        for (int reg = 0; reg < 4; ++reg) {
            int   m = g * 4 + reg;
            float v = fmaf(stats2[m][1], acc[reg] - stats2[m][0] * sn, cn);
            v = fmaxf(v, 0.f);
            *(short*)(tilebuf + ((m * 128 + n * 2) ^ ((m & 7) << 4))) = hbf(v);
        }
    }
    __syncthreads();

    // ---- up-GEMM (A = w_up fragment-major, B = down^T), 2-deep pipeline,
    //      sections of 64 d round-trip through obuf -> 4x256B coalesced stores
    short8 bd0 = *(const short8*)(tilebuf + ((r * 128 +  0 + g * 16) ^ swz));
    short8 bd1 = *(const short8*)(tilebuf + ((r * 128 + 64 + g * 16) ^ swz));

    const short* wupl = wup_perm + lane * 8;
    float (*ob)[65] = obuf[wid];
    // store-pass mapping: token t = q*4 + g  ->  row0 + g + q*4
    float* const outsec = out + (size_t)(row0 + g) * D_MODEL + wid * 512
                        + r * 4;

    short8 ua[2], ub[2];
    {
        int b16 = wid * 32;
        ua[0] = *(const short8*)(wupl + (size_t)(b16 * 2 + 0) * 512);
        ub[0] = *(const short8*)(wupl + (size_t)(b16 * 2 + 1) * 512);
    }
#pragma unroll
    for (int sec = 0; sec < 8; ++sec) {
#pragma unroll
        for (int q = 0; q < 4; ++q) {
            int i   = sec * 4 + q;
            int cur = i & 1;
            if (i < 31) {
                int b16 = wid * 32 + i + 1;
                ua[cur ^ 1] = *(const short8*)(wupl + (size_t)(b16 * 2 + 0) * 512);
                ub[cur ^ 1] = *(const short8*)(wupl + (size_t)(b16 * 2 + 1) * 512);
            }
            f32x4 o = (f32x4){0.f, 0.f, 0.f, 0.f};
            o = __builtin_amdgcn_mfma_f32_16x16x32_bf16(ua[cur], bd0, o, 0, 0, 0);
            o = __builtin_amdgcn_mfma_f32_16x16x32_bf16(ub[cur], bd1, o, 0, 0, 0);
            int dbase = (wid * 32 + i) * 16;
            f32x4 bu = *(const f32x4*)(b_up + dbase + g * 4);
            o += bu;
            // frag -> section buffer: token r, local d = q*16 + g*4
            *(f32x4*)&ob[r][q * 16 + g * 4] = o;
        }
        asm volatile("s_waitcnt lgkmcnt(0)" ::: "memory");  // section complete
        // store pass: 4 instrs, each 4 segments x 256B contiguous
#pragma unroll
        for (int q = 0; q < 4; ++q) {
            int t = q * 4 + g;                     // token row
            f32x4 v = *(const f32x4*)&ob[t][r * 4];
            *(f32x4*)(outsec + (size_t)(q * 4) * D_MODEL + sec * 64) = v;
        }
        asm volatile("s_waitcnt lgkmcnt(0)" ::: "memory");  // reads retired
    }
}

extern "C" void kernel_launch(void* const* d_in, const int* in_sizes, int n_in,
                              void* d_out, int out_size, void* d_ws, size_t ws_size,
                              hipStream_t stream) {
    const float* x      = (const float*)d_in[0];
    const float* gamma  = (const float*)d_in[1];
    const float* beta   = (const float*)d_in[2];
    const float* w_down = (const float*)d_in[3];
    const float* b_down = (const float*)d_in[4];
    const float* w_up   = (const float*)d_in[5];
    const float* b_up   = (const float*)d_in[6];
    float* out = (float*)d_out;

    char* ws = (char*)d_ws;
    short* wg_perm  = (short*)ws;                 // 256 KB
    short* wup_perm = (short*)(ws + 262144);      // 256 KB
    float* s_v  = (float*)(ws + 524288);          // 256 B
    float* c_v  = (float*)(ws + 524544);          // 256 B

    prep_kernel<<<128, 256, 0, stream>>>(w_down, gamma, beta, b_down, w_up,
                                         wg_perm, wup_perm, s_v, c_v);
    adapter_kernel<<<1024, 256, 0, stream>>>(x, b_up, wg_perm, wup_perm,
                                             s_v, c_v, out);
}